// Round 12
// baseline (385.975 us; speedup 1.0000x reference)
//
#include <hip/hip_runtime.h>
#include <hip/hip_fp16.h>
#include <math.h>

#define NN 50000
#define NE 800000
#define FT 128
#define NG 512
#define F1 512
#define F2 256
#define NC 32
#define BN_EPS 1e-5f
#define NSLC (NN / 8)                 // 6250 nodes per XCD dst-slice
#define NSTRIP ((NE + 2047) / 2048)   // 391 strips of 2048 edges
#define NBLK ((NN + 255) / 256)       // 196
#define NBH (NBLK * 64)               // block x bucket table

typedef __attribute__((ext_vector_type(8))) unsigned short ushort8;
typedef __attribute__((ext_vector_type(8))) _Float16 f16x8;
typedef __attribute__((ext_vector_type(4))) float f32x4;

__device__ __forceinline__ unsigned short f2h(float f) {
  return __half_as_ushort(__float2half(f));  // RNE
}
__device__ __forceinline__ float h2f(unsigned short h) {
  return __half2float(__ushort_as_half(h));
}

// ---------------- graph structure ----------------
// k_hist: strip-partitioned, per-XCD counter slices (atomics stay L2-local).

__global__ __launch_bounds__(256) void k_hist(const int* __restrict__ ei, int* __restrict__ cnt8,
                                              unsigned short* __restrict__ rank16) {
  int c = blockIdx.x & 7;
  int e0 = blockIdx.x * 2048 + threadIdx.x * 8;
  if (e0 >= NE) return;  // NE % 8 == 0 -> threads fully in or out
  int* cn = cnt8 + (size_t)c * NN;
  const int* dst = ei + NE;
  int4 a = *(const int4*)&dst[e0];
  int4 b4 = *(const int4*)&dst[e0 + 4];
  int d[8] = {a.x, a.y, a.z, a.w, b4.x, b4.y, b4.z, b4.w};
  ushort8 r;
#pragma unroll
  for (int j = 0; j < 8; ++j) r[j] = (unsigned short)atomicAdd(&cn[d[j]], 1);
  *(ushort8*)&rank16[e0] = r;
}

// total count + in-place exclusive prefix over 8 slices + dinv (fused)
__global__ __launch_bounds__(256) void k_sumdinv(int* __restrict__ cnt8, int* __restrict__ cnt,
                                                 float* __restrict__ dinv) {
  int n = blockIdx.x * 256 + threadIdx.x;
  if (n >= NN) return;
  int s = 0;
#pragma unroll
  for (int c = 0; c < 8; ++c) {
    int v = cnt8[(size_t)c * NN + n];
    cnt8[(size_t)c * NN + n] = s;  // exclusive prefix (slice base)
    s += v;
  }
  cnt[n] = s;
  dinv[n] = rsqrtf((float)(s + 1));  // +1 self loop
}

__global__ __launch_bounds__(256) void k_scan1(const int* __restrict__ cnt, int* __restrict__ bsum) {
  __shared__ int s[256];
  int t = threadIdx.x, i = blockIdx.x * 256 + t;
  s[t] = (i < NN) ? cnt[i] : 0;
  __syncthreads();
  for (int d = 128; d > 0; d >>= 1) {
    if (t < d) s[t] += s[t + d];
    __syncthreads();
  }
  if (t == 0) bsum[blockIdx.x] = s[0];
}

__global__ __launch_bounds__(256) void k_scan2(const int* __restrict__ bsum, int* __restrict__ bscan, int nb) {
  __shared__ int s[256];
  int t = threadIdx.x;
  int v = (t < nb) ? bsum[t] : 0;
  s[t] = v; __syncthreads();
  for (int d = 1; d < 256; d <<= 1) {
    int a = (t >= d) ? s[t - d] : 0;
    __syncthreads();
    s[t] += a;
    __syncthreads();
  }
  bscan[t] = s[t] - v;  // exclusive
}

__global__ __launch_bounds__(256) void k_scan3(const int* __restrict__ cnt, const int* __restrict__ bscan,
                                               int* __restrict__ off) {
  __shared__ int s[256];
  int t = threadIdx.x, i = blockIdx.x * 256 + t;
  int v = (i < NN) ? cnt[i] : 0;
  s[t] = v; __syncthreads();
  for (int d = 1; d < 256; d <<= 1) {
    int a = (t >= d) ? s[t - d] : 0;
    __syncthreads();
    s[t] += a;
    __syncthreads();
  }
  int base = bscan[blockIdx.x];
  if (i < NN) off[i] = base + s[t] - v;       // exclusive prefix
  if (i == NN - 1) off[NN] = base + s[t];     // total = NE
}

// k_fill: dst-range partitioned (XCD-local ep writes), zero atomics.
__global__ __launch_bounds__(256) void k_fill(const int* __restrict__ ei, const int* __restrict__ off,
                                              const int* __restrict__ pre8,
                                              const unsigned short* __restrict__ rank16,
                                              const float* __restrict__ dinv,
                                              unsigned int* __restrict__ ep) {
  int c = blockIdx.x & 7;
  int lo = c * NSLC, hi = lo + NSLC;
  int strip = blockIdx.x >> 3;
  int e0 = strip * 2048 + threadIdx.x * 8;
  if (e0 >= NE) return;
  const int* prec = pre8 + (size_t)(strip & 7) * NN;  // strip's XCD in k_hist
  const int* dst = ei + NE;
  int4 da = *(const int4*)&dst[e0];
  int4 db = *(const int4*)&dst[e0 + 4];
  int4 sa = *(const int4*)&ei[e0];
  int4 sb = *(const int4*)&ei[e0 + 4];
  ushort8 rr = *(const ushort8*)&rank16[e0];
  int d[8] = {da.x, da.y, da.z, da.w, db.x, db.y, db.z, db.w};
  int s[8] = {sa.x, sa.y, sa.z, sa.w, sb.x, sb.y, sb.z, sb.w};
#pragma unroll
  for (int j = 0; j < 8; ++j) {
    if (d[j] >= lo && d[j] < hi) {
      int p = off[d[j]] + prec[d[j]] + (int)rr[j];
      float w = dinv[s[j]] * dinv[d[j]];
      ep[p] = (unsigned int)(s[j] & 0xFFFF) | ((unsigned int)f2h(w) << 16);
    }
  }
}

// ---------------- degree-sorted perm, contention-free (CSR-style build) ----------
// bucket = min(deg,63); per-block LDS histogram -> global scan -> LDS-ranked scatter.

__global__ __launch_bounds__(256) void k_bhist(const int* __restrict__ cnt, int* __restrict__ bh) {
  __shared__ int lh[64];
  int t = threadIdx.x;
  if (t < 64) lh[t] = 0;
  __syncthreads();
  int i = blockIdx.x * 256 + t;
  if (i < NN) atomicAdd(&lh[min(cnt[i], 63)], 1);
  __syncthreads();
  if (t < 64) bh[blockIdx.x * 64 + t] = lh[t];
}

// scan over j = bucket*NBLK + blk (bucket-major), one block
__global__ __launch_bounds__(256) void k_bscan(const int* __restrict__ bh, int* __restrict__ gb) {
  __shared__ int s[256];
  __shared__ int carry;
  int t = threadIdx.x;
  if (t == 0) carry = 0;
  for (int base = 0; base < NBH; base += 256) {
    __syncthreads();
    int cloc = carry;
    int j = base + t;
    int b = j / NBLK, blk = j % NBLK;
    int v = (j < NBH) ? bh[blk * 64 + b] : 0;
    s[t] = v; __syncthreads();
    for (int d = 1; d < 256; d <<= 1) {
      int a = (t >= d) ? s[t - d] : 0;
      __syncthreads();
      s[t] += a;
      __syncthreads();
    }
    if (j < NBH) gb[blk * 64 + b] = cloc + s[t] - v;  // exclusive
    __syncthreads();
    if (t == 0) carry = cloc + s[255];
  }
}

__global__ __launch_bounds__(256) void k_dscatter(const int* __restrict__ cnt, const int* __restrict__ gb,
                                                  int* __restrict__ perm) {
  __shared__ int lcur[64];
  int t = threadIdx.x;
  if (t < 64) lcur[t] = 0;
  __syncthreads();
  int i = blockIdx.x * 256 + t;
  if (i < NN) {
    int b = min(cnt[i], 63);
    int r = atomicAdd(&lcur[b], 1);  // LDS atomic, ~4-way avg
    perm[gb[blockIdx.x * 64 + b] + r] = i;
  }
}

// ---------------- W prep (all 4 layers): fp32 [k][n] -> fp16 [n][k], pre-swizzled ----

__global__ __launch_bounds__(256) void k_wprep4(const float* __restrict__ W0, const float* __restrict__ W1,
                                                const float* __restrict__ W2, const float* __restrict__ W3,
                                                unsigned short* __restrict__ Wt) {
  int idx = blockIdx.x * 256 + threadIdx.x;  // 65536
  int l = idx >> 14;
  int r = idx & 16383;
  int c = r >> 7, k = r & 127;
  const float* W = (l == 0) ? W0 : (l == 1) ? W1 : (l == 2) ? W2 : W3;
  int byte = c * 256 + k * 2;
  byte ^= (c & 7) << 4;
  Wt[l * 16384 + (byte >> 1)] = f2h(W[k * FT + c]);
}

// ---------------- GCN layer: MFMA GEMM (h = x @ W), chunk-major fp16 output --------

template <int FIRST>
__global__ __launch_bounds__(256) void k_gemm_mfma(const float* __restrict__ Xf,
                                                   const unsigned short* __restrict__ Xh,
                                                   const unsigned short* __restrict__ Wt,
                                                   unsigned short* __restrict__ Oc) {
  __shared__ unsigned short sA[64 * 128];
  __shared__ unsigned short sB[128 * 128];
  int t = threadIdx.x;
  // stage B (32KB, linear copy of pre-swizzled Wt)
#pragma unroll
  for (int i = 0; i < 8; ++i) {
    int off = t * 16 + i * 4096;  // bytes
    *(float4*)((char*)sB + off) = *(const float4*)((const char*)Wt + off);
  }
  // stage A (64 rows x 128 k, fp16, swizzled)
  {
    int row = t >> 2, k0 = (t & 3) * 32;
    int grow = blockIdx.x * 64 + row;
    if (grow >= NN) grow = NN - 1;  // clamp; outputs guarded below
    if (FIRST) {
      const float* xr = Xf + (size_t)grow * FT + k0;
#pragma unroll
      for (int j = 0; j < 4; ++j) {
        float4 v0 = *(const float4*)&xr[j * 8];
        float4 v1 = *(const float4*)&xr[j * 8 + 4];
        ushort8 w;
        w[0] = f2h(v0.x); w[1] = f2h(v0.y); w[2] = f2h(v0.z); w[3] = f2h(v0.w);
        w[4] = f2h(v1.x); w[5] = f2h(v1.y); w[6] = f2h(v1.z); w[7] = f2h(v1.w);
        int byte = row * 256 + (k0 + j * 8) * 2;
        byte ^= (row & 7) << 4;
        *(ushort8*)((char*)sA + byte) = w;
      }
    } else {
#pragma unroll
      for (int j = 0; j < 4; ++j) {
        int k = k0 + j * 8;
        int ch = k >> 5, ko = k & 31;
        ushort8 v = *(const ushort8*)&Xh[((size_t)ch * NN + grow) * 32 + ko];
        int byte = row * 256 + k * 2;
        byte ^= (row & 7) << 4;
        *(ushort8*)((char*)sA + byte) = v;
      }
    }
  }
  __syncthreads();
  int w = t >> 6, l = t & 63;
  int m = l & 15, ks = l >> 4;
  f16x8 a[4];
#pragma unroll
  for (int kk = 0; kk < 4; ++kk) {
    int r = w * 16 + m;
    int byte = r * 256 + (kk * 32 + ks * 8) * 2;
    byte ^= (r & 7) << 4;
    a[kk] = *(const f16x8*)((const char*)sA + byte);
  }
  f32x4 acc[8];
#pragma unroll
  for (int nf = 0; nf < 8; ++nf) acc[nf] = (f32x4){0.f, 0.f, 0.f, 0.f};
#pragma unroll
  for (int nf = 0; nf < 8; ++nf) {
#pragma unroll
    for (int kk = 0; kk < 4; ++kk) {
      int col = nf * 16 + m;
      int byte = col * 256 + (kk * 32 + ks * 8) * 2;
      byte ^= (col & 7) << 4;
      f16x8 b = *(const f16x8*)((const char*)sB + byte);
      acc[nf] = __builtin_amdgcn_mfma_f32_16x16x32_f16(a[kk], b, acc[nf], 0, 0, 0);
    }
  }
  // epilogue: C/D layout col = lane&15, row = (lane>>4)*4 + reg  [m89-verified, dtype-indep]
  int orow0 = blockIdx.x * 64 + w * 16 + ks * 4;
#pragma unroll
  for (int nf = 0; nf < 8; ++nf) {
    int ch = nf >> 1;
    int co = ((nf & 1) << 4) + m;
#pragma unroll
    for (int r = 0; r < 4; ++r) {
      int orow = orow0 + r;
      if (orow < NN) Oc[((size_t)ch * NN + orow) * 32 + co] = f2h(acc[nf][r]);
    }
  }
}

// ---------------- GCN layer: aggregate, degree-sorted nodes, XCD pinned ------------
// chunk c = blockIdx.x & 3, 64 nodes/block via perm (wave's 16 nodes ~equal degree
// -> lockstep edge loops), 4 lanes/node, 64B coalesced row per edge gather.

__global__ __launch_bounds__(256) void k_aggc(const unsigned short* __restrict__ Hc,
                                              const float* __restrict__ dinv,
                                              const int* __restrict__ off, const unsigned int* __restrict__ ep,
                                              const int* __restrict__ perm,
                                              const float* __restrict__ bias, unsigned short* __restrict__ O) {
  int c = blockIdx.x & 3;
  int grp = blockIdx.x >> 2;
  int t = threadIdx.x;
  int idx = grp * 64 + (t >> 2);
  int l = t & 3;
  if (idx >= NN) return;
  int node = perm[idx];
  const unsigned short* base = Hc + (size_t)c * NN * 32 + l * 8;
  float di = dinv[node];
  float sw = di * di;  // self-loop norm
  float acc[8];
  {
    ushort8 sv = *(const ushort8*)&base[(size_t)node * 32];
#pragma unroll
    for (int i = 0; i < 8; ++i) acc[i] = h2f(sv[i]) * sw;
  }
  int e0 = off[node], e1 = off[node + 1];
  int e = e0;
  for (; e + 8 <= e1; e += 8) {
    unsigned int pw[8];
#pragma unroll
    for (int j = 0; j < 8; ++j) pw[j] = ep[e + j];
    ushort8 v[8];
#pragma unroll
    for (int j = 0; j < 8; ++j) v[j] = *(const ushort8*)&base[(size_t)(pw[j] & 0xFFFFu) * 32];
#pragma unroll
    for (int j = 0; j < 8; ++j) {
      float w = h2f((unsigned short)(pw[j] >> 16));
#pragma unroll
      for (int i = 0; i < 8; ++i) acc[i] += h2f(v[j][i]) * w;
    }
  }
  for (; e + 4 <= e1; e += 4) {
    unsigned int p0 = ep[e], p1 = ep[e + 1], p2 = ep[e + 2], p3 = ep[e + 3];
    ushort8 v0 = *(const ushort8*)&base[(size_t)(p0 & 0xFFFFu) * 32];
    ushort8 v1 = *(const ushort8*)&base[(size_t)(p1 & 0xFFFFu) * 32];
    ushort8 v2 = *(const ushort8*)&base[(size_t)(p2 & 0xFFFFu) * 32];
    ushort8 v3 = *(const ushort8*)&base[(size_t)(p3 & 0xFFFFu) * 32];
    float w0 = h2f((unsigned short)(p0 >> 16));
    float w1 = h2f((unsigned short)(p1 >> 16));
    float w2 = h2f((unsigned short)(p2 >> 16));
    float w3 = h2f((unsigned short)(p3 >> 16));
#pragma unroll
    for (int i = 0; i < 8; ++i) acc[i] += h2f(v0[i]) * w0;
#pragma unroll
    for (int i = 0; i < 8; ++i) acc[i] += h2f(v1[i]) * w1;
#pragma unroll
    for (int i = 0; i < 8; ++i) acc[i] += h2f(v2[i]) * w2;
#pragma unroll
    for (int i = 0; i < 8; ++i) acc[i] += h2f(v3[i]) * w3;
  }
  for (; e < e1; ++e) {
    unsigned int pv = ep[e];
    float w = h2f((unsigned short)(pv >> 16));
    ushort8 v = *(const ushort8*)&base[(size_t)(pv & 0xFFFFu) * 32];
#pragma unroll
    for (int i = 0; i < 8; ++i) acc[i] += h2f(v[i]) * w;
  }
  ushort8 outv;
#pragma unroll
  for (int i = 0; i < 8; ++i) {
    float v = acc[i] + bias[c * 32 + l * 8 + i];
    outv[i] = f2h(fmaxf(v, 0.f));
  }
  *(ushort8*)&O[((size_t)c * NN + node) * 32 + l * 8] = outv;
}

// ---------------- pooling (fp16 chunk-major input) ----------------

__global__ __launch_bounds__(256) void k_bounds(const int* __restrict__ batch, int* __restrict__ gstart,
                                                int* __restrict__ gend) {
  int i = blockIdx.x * 256 + threadIdx.x;
  if (i >= NN) return;
  int b = batch[i];
  if (i == 0 || batch[i - 1] != b) gstart[b] = i;
  if (i == NN - 1 || batch[i + 1] != b) gend[b] = i + 1;
}

__global__ __launch_bounds__(128) void k_pool(const unsigned short* __restrict__ X, const int* __restrict__ gstart,
                                              const int* __restrict__ gend, float* __restrict__ pool) {
  int g = blockIdx.x, t = threadIdx.x;
  int ch = t >> 5, wo = t & 31;
  float s = 0.f;
  int n0 = gstart[g], n1 = gend[g];
  const unsigned short* base = X + (size_t)ch * NN * 32 + wo;
  for (int n = n0; n < n1; ++n) s += h2f(base[(size_t)n * 32]);
  pool[g * FT + t] = s;
}

// ---------------- MLP head ----------------

__global__ __launch_bounds__(256) void k_fc1(const float* __restrict__ P, const float* __restrict__ W,
                                             const float* __restrict__ B, float* __restrict__ O) {
  __shared__ float sp[FT];
  int g = blockIdx.x, t = threadIdx.x;
  if (t < FT) sp[t] = P[g * FT + t];
  __syncthreads();
  float a0 = B[t], a1 = B[t + 256];
  for (int k = 0; k < FT; ++k) {
    float x = sp[k];
    a0 += x * W[k * F1 + t];
    a1 += x * W[k * F1 + t + 256];
  }
  O[g * F1 + t] = fmaxf(a0, 0.f);
  O[g * F1 + t + 256] = fmaxf(a1, 0.f);
}

__global__ __launch_bounds__(256) void k_bnstats(const float* __restrict__ h, int cols,
                                                 float* __restrict__ bm, float* __restrict__ br) {
  __shared__ float ss[256], s2[256];
  int c = blockIdx.x, t = threadIdx.x;
  float a = 0.f, b = 0.f;
  for (int r = t; r < NG; r += 256) {
    float v = h[r * cols + c];
    a += v; b += v * v;
  }
  ss[t] = a; s2[t] = b; __syncthreads();
  for (int d = 128; d > 0; d >>= 1) {
    if (t < d) { ss[t] += ss[t + d]; s2[t] += s2[t + d]; }
    __syncthreads();
  }
  if (t == 0) {
    float m = ss[0] / NG;
    float var = s2[0] / NG - m * m;
    bm[c] = m;
    br[c] = rsqrtf(var + BN_EPS);
  }
}

__global__ __launch_bounds__(256) void k_fc2(const float* __restrict__ H1, const float* __restrict__ bm,
                                             const float* __restrict__ br, const float* __restrict__ gam,
                                             const float* __restrict__ bet, const float* __restrict__ W,
                                             const float* __restrict__ B, float* __restrict__ O) {
  __shared__ float sh[F1];
  int g = blockIdx.x, t = threadIdx.x;
  for (int k = t; k < F1; k += 256) {
    float v = H1[g * F1 + k];
    sh[k] = (v - bm[k]) * br[k] * gam[k] + bet[k];
  }
  __syncthreads();
  float a = B[t];
  for (int k = 0; k < F1; ++k) a += sh[k] * W[k * F2 + t];
  O[g * F2 + t] = fmaxf(a, 0.f);
}

__global__ __launch_bounds__(256) void k_fc3(const float* __restrict__ H2, const float* __restrict__ bm,
                                             const float* __restrict__ br, const float* __restrict__ gam,
                                             const float* __restrict__ bet, const float* __restrict__ W,
                                             const float* __restrict__ B, float* __restrict__ O) {
  __shared__ float sh[F2];
  int g = blockIdx.x, t = threadIdx.x;
  if (t < F2) {
    float v = H2[g * F2 + t];
    sh[t] = (v - bm[t]) * br[t] * gam[t] + bet[t];
  }
  __syncthreads();
  if (t < NC) {
    float a = B[t];
    for (int k = 0; k < F2; ++k) a += sh[k] * W[k * NC + t];
    O[g * NC + t] = 1.f / (1.f + expf(-a));
  }
}

// ---------------- launch ----------------

extern "C" void kernel_launch(void* const* d_in, const int* in_sizes, int n_in,
                              void* d_out, int out_size, void* d_ws, size_t ws_size,
                              hipStream_t stream) {
  const float* x     = (const float*)d_in[0];
  const int*   ei    = (const int*)d_in[1];
  const int*   batch = (const int*)d_in[2];
  const float* Wc[4] = {(const float*)d_in[3], (const float*)d_in[5], (const float*)d_in[7], (const float*)d_in[9]};
  const float* Bc[4] = {(const float*)d_in[4], (const float*)d_in[6], (const float*)d_in[8], (const float*)d_in[10]};
  const float* lw1 = (const float*)d_in[11]; const float* lb1 = (const float*)d_in[12];
  const float* lw2 = (const float*)d_in[13]; const float* lb2 = (const float*)d_in[14];
  const float* lw3 = (const float*)d_in[15]; const float* lb3 = (const float*)d_in[16];
  const float* g1  = (const float*)d_in[17]; const float* be1 = (const float*)d_in[18];
  const float* g2  = (const float*)d_in[19]; const float* be2 = (const float*)d_in[20];

  char* p = (char*)d_ws;
  auto take = [&](size_t bytes) {
    char* r = p;
    p += (bytes + 255) & ~(size_t)255;
    return r;
  };
  int*   cnt8   = (int*)take((size_t)8 * NN * 4);
  int*   cnt    = (int*)take((size_t)NN * 4);
  float* dinv   = (float*)take((size_t)NN * 4);
  int*   off    = (int*)take((size_t)(NN + 1) * 4);
  int*   bsum   = (int*)take(256 * 4);
  int*   bscan  = (int*)take(256 * 4);
  int*   gstart = (int*)take((size_t)NG * 4);
  int*   gend   = (int*)take((size_t)NG * 4);
  int*   bh     = (int*)take((size_t)NBH * 4);
  int*   gb     = (int*)take((size_t)NBH * 4);
  int*   perm   = (int*)take((size_t)NN * 4);
  unsigned short* rank16 = (unsigned short*)take((size_t)NE * 2);
  unsigned int*   ep   = (unsigned int*)take((size_t)NE * 4);
  unsigned short* Wt   = (unsigned short*)take((size_t)4 * FT * FT * 2);
  unsigned short* bufT = (unsigned short*)take((size_t)NN * FT * 2);  // chunk-major fp16
  unsigned short* bufA = (unsigned short*)take((size_t)NN * FT * 2);
  unsigned short* bufB = (unsigned short*)take((size_t)NN * FT * 2);
  float* pool   = (float*)take((size_t)NG * FT * 4);
  float* h1     = (float*)take((size_t)NG * F1 * 4);
  float* h2     = (float*)take((size_t)NG * F2 * 4);
  float* bnm1   = (float*)take(F1 * 4);
  float* bnr1   = (float*)take(F1 * 4);
  float* bnm2   = (float*)take(F2 * 4);
  float* bnr2   = (float*)take(F2 * 4);

  hipMemsetAsync(cnt8, 0, (size_t)8 * NN * 4, stream);
  hipMemsetAsync(gstart, 0, (size_t)NG * 4, stream);
  hipMemsetAsync(gend, 0, (size_t)NG * 4, stream);

  k_hist<<<NSTRIP, 256, 0, stream>>>(ei, cnt8, rank16);
  k_sumdinv<<<NBLK, 256, 0, stream>>>(cnt8, cnt, dinv);
  k_scan1<<<NBLK, 256, 0, stream>>>(cnt, bsum);
  k_scan2<<<1, 256, 0, stream>>>(bsum, bscan, NBLK);
  k_scan3<<<NBLK, 256, 0, stream>>>(cnt, bscan, off);
  k_fill<<<NSTRIP * 8, 256, 0, stream>>>(ei, off, cnt8, rank16, dinv, ep);
  k_bhist<<<NBLK, 256, 0, stream>>>(cnt, bh);
  k_bscan<<<1, 256, 0, stream>>>(bh, gb);
  k_dscatter<<<NBLK, 256, 0, stream>>>(cnt, gb, perm);
  k_wprep4<<<256, 256, 0, stream>>>(Wc[0], Wc[1], Wc[2], Wc[3], Wt);

  const int NBLK_G = (NN + 63) / 64;    // 782
  const int NGRP_A = (NN + 63) / 64;    // 782
  unsigned short* outs[4] = {bufA, bufB, bufA, bufB};
  for (int l = 0; l < 4; ++l) {
    if (l == 0)
      k_gemm_mfma<1><<<NBLK_G, 256, 0, stream>>>(x, (const unsigned short*)nullptr, Wt, bufT);
    else
      k_gemm_mfma<0><<<NBLK_G, 256, 0, stream>>>((const float*)nullptr, outs[l - 1], Wt + (size_t)l * FT * FT, bufT);
    k_aggc<<<NGRP_A * 4, 256, 0, stream>>>(bufT, dinv, off, ep, perm, Bc[l], outs[l]);
  }

  k_bounds<<<NBLK, 256, 0, stream>>>(batch, gstart, gend);
  k_pool<<<NG, 128, 0, stream>>>(bufB, gstart, gend, pool);

  k_fc1<<<NG, 256, 0, stream>>>(pool, lw1, lb1, h1);
  k_bnstats<<<F1, 256, 0, stream>>>(h1, F1, bnm1, bnr1);
  k_fc2<<<NG, 256, 0, stream>>>(h1, bnm1, bnr1, g1, be1, lw2, lb2, h2);
  k_bnstats<<<F2, 256, 0, stream>>>(h2, F2, bnm2, bnr2);
  k_fc3<<<NG, 256, 0, stream>>>(h2, bnm2, bnr2, g2, be2, lw3, lb3, (float*)d_out);
}

// Round 13
// 305.341 us; speedup vs baseline: 1.2641x; 1.2641x over previous
//
#include <hip/hip_runtime.h>
#include <hip/hip_fp16.h>
#include <math.h>

#define NN 50000
#define NE 800000
#define FT 128
#define NG 512
#define F1 512
#define F2 256
#define NC 32
#define BN_EPS 1e-5f
#define NSLC (NN / 8)                 // 6250 nodes per XCD dst-slice
#define NSTRIP ((NE + 2047) / 2048)   // 391 strips of 2048 edges
#define NBLK ((NN + 255) / 256)       // 196

typedef __attribute__((ext_vector_type(8))) unsigned short ushort8;
typedef __attribute__((ext_vector_type(8))) _Float16 f16x8;
typedef __attribute__((ext_vector_type(4))) float f32x4;

__device__ __forceinline__ unsigned short f2h(float f) {
  return __half_as_ushort(__float2half(f));  // RNE
}
__device__ __forceinline__ float h2f(unsigned short h) {
  return __half2float(__ushort_as_half(h));
}

// ---------------- graph structure ----------------
// k_hist: strip-partitioned, per-XCD counter slices (atomics stay L2-local).

__global__ __launch_bounds__(256) void k_hist(const int* __restrict__ ei, int* __restrict__ cnt8,
                                              unsigned short* __restrict__ rank16) {
  int c = blockIdx.x & 7;
  int e0 = blockIdx.x * 2048 + threadIdx.x * 8;
  if (e0 >= NE) return;  // NE % 8 == 0 -> threads fully in or out
  int* cn = cnt8 + (size_t)c * NN;
  const int* dst = ei + NE;
  int4 a = *(const int4*)&dst[e0];
  int4 b4 = *(const int4*)&dst[e0 + 4];
  int d[8] = {a.x, a.y, a.z, a.w, b4.x, b4.y, b4.z, b4.w};
  ushort8 r;
#pragma unroll
  for (int j = 0; j < 8; ++j) r[j] = (unsigned short)atomicAdd(&cn[d[j]], 1);
  *(ushort8*)&rank16[e0] = r;
}

// fused: slice prefix + total cnt + dinv + per-block sum (feeds scan2)
__global__ __launch_bounds__(256) void k_sumdinv(int* __restrict__ cnt8, int* __restrict__ cnt,
                                                 float* __restrict__ dinv, int* __restrict__ bsum) {
  __shared__ int sh[256];
  int t = threadIdx.x, n = blockIdx.x * 256 + t;
  int tot = 0;
  if (n < NN) {
    int s = 0;
#pragma unroll
    for (int c = 0; c < 8; ++c) {
      int v = cnt8[(size_t)c * NN + n];
      cnt8[(size_t)c * NN + n] = s;  // exclusive prefix (slice base)
      s += v;
    }
    cnt[n] = s;
    dinv[n] = rsqrtf((float)(s + 1));  // +1 self loop
    tot = s;
  }
  sh[t] = tot;
  __syncthreads();
  for (int d = 128; d > 0; d >>= 1) {
    if (t < d) sh[t] += sh[t + d];
    __syncthreads();
  }
  if (t == 0) bsum[blockIdx.x] = sh[0];
}

__global__ __launch_bounds__(256) void k_scan2(const int* __restrict__ bsum, int* __restrict__ bscan, int nb) {
  __shared__ int s[256];
  int t = threadIdx.x;
  int v = (t < nb) ? bsum[t] : 0;
  s[t] = v; __syncthreads();
  for (int d = 1; d < 256; d <<= 1) {
    int a = (t >= d) ? s[t - d] : 0;
    __syncthreads();
    s[t] += a;
    __syncthreads();
  }
  bscan[t] = s[t] - v;  // exclusive
}

__global__ __launch_bounds__(256) void k_scan3(const int* __restrict__ cnt, const int* __restrict__ bscan,
                                               int* __restrict__ off) {
  __shared__ int s[256];
  int t = threadIdx.x, i = blockIdx.x * 256 + t;
  int v = (i < NN) ? cnt[i] : 0;
  s[t] = v; __syncthreads();
  for (int d = 1; d < 256; d <<= 1) {
    int a = (t >= d) ? s[t - d] : 0;
    __syncthreads();
    s[t] += a;
    __syncthreads();
  }
  int base = bscan[blockIdx.x];
  if (i < NN) off[i] = base + s[t] - v;       // exclusive prefix
  if (i == NN - 1) off[NN] = base + s[t];     // total = NE
}

// k_fill: dst-range partitioned (XCD-local ep writes), zero atomics.
__global__ __launch_bounds__(256) void k_fill(const int* __restrict__ ei, const int* __restrict__ off,
                                              const int* __restrict__ pre8,
                                              const unsigned short* __restrict__ rank16,
                                              const float* __restrict__ dinv,
                                              unsigned int* __restrict__ ep) {
  int c = blockIdx.x & 7;
  int lo = c * NSLC, hi = lo + NSLC;
  int strip = blockIdx.x >> 3;
  int e0 = strip * 2048 + threadIdx.x * 8;
  if (e0 >= NE) return;
  const int* prec = pre8 + (size_t)(strip & 7) * NN;  // strip's XCD in k_hist
  const int* dst = ei + NE;
  int4 da = *(const int4*)&dst[e0];
  int4 db = *(const int4*)&dst[e0 + 4];
  int4 sa = *(const int4*)&ei[e0];
  int4 sb = *(const int4*)&ei[e0 + 4];
  ushort8 rr = *(const ushort8*)&rank16[e0];
  int d[8] = {da.x, da.y, da.z, da.w, db.x, db.y, db.z, db.w};
  int s[8] = {sa.x, sa.y, sa.z, sa.w, sb.x, sb.y, sb.z, sb.w};
#pragma unroll
  for (int j = 0; j < 8; ++j) {
    if (d[j] >= lo && d[j] < hi) {
      int p = off[d[j]] + prec[d[j]] + (int)rr[j];
      float w = dinv[s[j]] * dinv[d[j]];
      ep[p] = (unsigned int)(s[j] & 0xFFFF) | ((unsigned int)f2h(w) << 16);
    }
  }
}

// ---------------- W prep (all 4 layers): fp32 [k][n] -> fp16 [n][k], pre-swizzled ----

__global__ __launch_bounds__(256) void k_wprep4(const float* __restrict__ W0, const float* __restrict__ W1,
                                                const float* __restrict__ W2, const float* __restrict__ W3,
                                                unsigned short* __restrict__ Wt) {
  int idx = blockIdx.x * 256 + threadIdx.x;  // 65536
  int l = idx >> 14;
  int r = idx & 16383;
  int c = r >> 7, k = r & 127;
  const float* W = (l == 0) ? W0 : (l == 1) ? W1 : (l == 2) ? W2 : W3;
  int byte = c * 256 + k * 2;
  byte ^= (c & 7) << 4;
  Wt[l * 16384 + (byte >> 1)] = f2h(W[k * FT + c]);
}

// ---------------- GCN layer: MFMA GEMM (h = x @ W), chunk-major fp16 output --------
// 64 rows/block, 4 waves x (16 rows x 128 cols), mfma_f32_16x16x32_f16.
// Epilogue: C-tile round-trips through LDS (reusing sA) -> 4x16B coalesced
// stores per thread instead of 32x2B scattered stores.

template <int FIRST>
__global__ __launch_bounds__(256) void k_gemm_mfma(const float* __restrict__ Xf,
                                                   const unsigned short* __restrict__ Xh,
                                                   const unsigned short* __restrict__ Wt,
                                                   unsigned short* __restrict__ Oc) {
  __shared__ unsigned short sA[64 * 128];
  __shared__ unsigned short sB[128 * 128];
  int t = threadIdx.x;
  // stage B (32KB, linear copy of pre-swizzled Wt)
#pragma unroll
  for (int i = 0; i < 8; ++i) {
    int off = t * 16 + i * 4096;  // bytes
    *(float4*)((char*)sB + off) = *(const float4*)((const char*)Wt + off);
  }
  // stage A (64 rows x 128 k, fp16, swizzled byte ^= (row&7)<<4)
  {
    int row = t >> 2, k0 = (t & 3) * 32;
    int grow = blockIdx.x * 64 + row;
    if (grow >= NN) grow = NN - 1;  // clamp; outputs guarded below
    if (FIRST) {
      const float* xr = Xf + (size_t)grow * FT + k0;
#pragma unroll
      for (int j = 0; j < 4; ++j) {
        float4 v0 = *(const float4*)&xr[j * 8];
        float4 v1 = *(const float4*)&xr[j * 8 + 4];
        ushort8 w;
        w[0] = f2h(v0.x); w[1] = f2h(v0.y); w[2] = f2h(v0.z); w[3] = f2h(v0.w);
        w[4] = f2h(v1.x); w[5] = f2h(v1.y); w[6] = f2h(v1.z); w[7] = f2h(v1.w);
        int byte = row * 256 + (k0 + j * 8) * 2;
        byte ^= (row & 7) << 4;
        *(ushort8*)((char*)sA + byte) = w;
      }
    } else {
#pragma unroll
      for (int j = 0; j < 4; ++j) {
        int k = k0 + j * 8;
        int ch = k >> 5, ko = k & 31;
        ushort8 v = *(const ushort8*)&Xh[((size_t)ch * NN + grow) * 32 + ko];
        int byte = row * 256 + k * 2;
        byte ^= (row & 7) << 4;
        *(ushort8*)((char*)sA + byte) = v;
      }
    }
  }
  __syncthreads();
  int w = t >> 6, l = t & 63;
  int m = l & 15, ks = l >> 4;
  f16x8 a[4];
#pragma unroll
  for (int kk = 0; kk < 4; ++kk) {
    int r = w * 16 + m;
    int byte = r * 256 + (kk * 32 + ks * 8) * 2;
    byte ^= (r & 7) << 4;
    a[kk] = *(const f16x8*)((const char*)sA + byte);
  }
  f32x4 acc[8];
#pragma unroll
  for (int nf = 0; nf < 8; ++nf) acc[nf] = (f32x4){0.f, 0.f, 0.f, 0.f};
#pragma unroll
  for (int nf = 0; nf < 8; ++nf) {
#pragma unroll
    for (int kk = 0; kk < 4; ++kk) {
      int col = nf * 16 + m;
      int byte = col * 256 + (kk * 32 + ks * 8) * 2;
      byte ^= (col & 7) << 4;
      f16x8 b = *(const f16x8*)((const char*)sB + byte);
      acc[nf] = __builtin_amdgcn_mfma_f32_16x16x32_f16(a[kk], b, acc[nf], 0, 0, 0);
    }
  }
  // epilogue: C/D layout col = lane&15, row = (lane>>4)*4 + reg  [m89-verified]
  __syncthreads();  // all waves done reading sA
  int lrow0 = w * 16 + ks * 4;  // block-local row base
#pragma unroll
  for (int nf = 0; nf < 8; ++nf) {
#pragma unroll
    for (int r = 0; r < 4; ++r) {
      sA[(lrow0 + r) * 128 + nf * 16 + m] = f2h(acc[nf][r]);
    }
  }
  __syncthreads();
  {
    int row = t >> 2, chp = t & 3;
    int grow2 = blockIdx.x * 64 + row;
    if (grow2 < NN) {
      const unsigned short* srcp = &sA[row * 128 + chp * 32];
      unsigned short* dstp = &Oc[((size_t)chp * NN + grow2) * 32];
#pragma unroll
      for (int q = 0; q < 4; ++q)
        *(ushort8*)&dstp[q * 8] = *(const ushort8*)&srcp[q * 8];
    }
  }
}

// ---------------- GCN layer: aggregate, fp16 4x32-feature chunks, XCD pinned -------
// chunk c = blockIdx.x & 3 (-> XCDs {c, c+4}), 64 nodes/block, 4 lanes/node,
// 64B coalesced row per edge gather. Per-XCD slice = 3.2MB -> L2-resident.

__global__ __launch_bounds__(256) void k_aggc(const unsigned short* __restrict__ Hc,
                                              const float* __restrict__ dinv,
                                              const int* __restrict__ off, const unsigned int* __restrict__ ep,
                                              const float* __restrict__ bias, unsigned short* __restrict__ O) {
  int c = blockIdx.x & 3;
  int grp = blockIdx.x >> 2;
  int t = threadIdx.x;
  int node = grp * 64 + (t >> 2);
  int l = t & 3;
  if (node >= NN) return;
  const unsigned short* base = Hc + (size_t)c * NN * 32 + l * 8;
  float di = dinv[node];
  float sw = di * di;  // self-loop norm
  float acc[8];
  {
    ushort8 sv = *(const ushort8*)&base[(size_t)node * 32];
#pragma unroll
    for (int i = 0; i < 8; ++i) acc[i] = h2f(sv[i]) * sw;
  }
  int e0 = off[node], e1 = off[node + 1];
  int e = e0;
  for (; e + 8 <= e1; e += 8) {
    unsigned int pw[8];
#pragma unroll
    for (int j = 0; j < 8; ++j) pw[j] = ep[e + j];
    ushort8 v[8];
#pragma unroll
    for (int j = 0; j < 8; ++j) v[j] = *(const ushort8*)&base[(size_t)(pw[j] & 0xFFFFu) * 32];
#pragma unroll
    for (int j = 0; j < 8; ++j) {
      float w = h2f((unsigned short)(pw[j] >> 16));
#pragma unroll
      for (int i = 0; i < 8; ++i) acc[i] += h2f(v[j][i]) * w;
    }
  }
  for (; e + 4 <= e1; e += 4) {
    unsigned int p0 = ep[e], p1 = ep[e + 1], p2 = ep[e + 2], p3 = ep[e + 3];
    ushort8 v0 = *(const ushort8*)&base[(size_t)(p0 & 0xFFFFu) * 32];
    ushort8 v1 = *(const ushort8*)&base[(size_t)(p1 & 0xFFFFu) * 32];
    ushort8 v2 = *(const ushort8*)&base[(size_t)(p2 & 0xFFFFu) * 32];
    ushort8 v3 = *(const ushort8*)&base[(size_t)(p3 & 0xFFFFu) * 32];
    float w0 = h2f((unsigned short)(p0 >> 16));
    float w1 = h2f((unsigned short)(p1 >> 16));
    float w2 = h2f((unsigned short)(p2 >> 16));
    float w3 = h2f((unsigned short)(p3 >> 16));
#pragma unroll
    for (int i = 0; i < 8; ++i) acc[i] += h2f(v0[i]) * w0;
#pragma unroll
    for (int i = 0; i < 8; ++i) acc[i] += h2f(v1[i]) * w1;
#pragma unroll
    for (int i = 0; i < 8; ++i) acc[i] += h2f(v2[i]) * w2;
#pragma unroll
    for (int i = 0; i < 8; ++i) acc[i] += h2f(v3[i]) * w3;
  }
  for (; e < e1; ++e) {
    unsigned int pv = ep[e];
    float w = h2f((unsigned short)(pv >> 16));
    ushort8 v = *(const ushort8*)&base[(size_t)(pv & 0xFFFFu) * 32];
#pragma unroll
    for (int i = 0; i < 8; ++i) acc[i] += h2f(v[i]) * w;
  }
  ushort8 outv;
#pragma unroll
  for (int i = 0; i < 8; ++i) {
    float v = acc[i] + bias[c * 32 + l * 8 + i];
    outv[i] = f2h(fmaxf(v, 0.f));
  }
  *(ushort8*)&O[((size_t)c * NN + node) * 32 + l * 8] = outv;
}

// ---------------- pooling + fc1 (fused; per-graph bounds via binary search) --------

__global__ __launch_bounds__(256) void k_poolfc1(const unsigned short* __restrict__ X,
                                                 const int* __restrict__ batch,
                                                 const float* __restrict__ W, const float* __restrict__ B,
                                                 float* __restrict__ O) {
  __shared__ float part[256];
  __shared__ float sp[FT];
  __shared__ int nb[2];
  int g = blockIdx.x, t = threadIdx.x;
  if (t < 2) {
    int val = g + t;
    int lo = 0, hi = NN;
    while (lo < hi) {
      int mid = (lo + hi) >> 1;
      if (batch[mid] < val) lo = mid + 1; else hi = mid;
    }
    nb[t] = lo;
  }
  __syncthreads();
  int n0 = nb[0], n1 = nb[1];
  int f = t & 127, half = t >> 7;
  int ch = f >> 5, wo = f & 31;
  const unsigned short* base = X + (size_t)ch * NN * 32 + wo;
  float s = 0.f;
  for (int n = n0 + half; n < n1; n += 2) s += h2f(base[(size_t)n * 32]);
  part[t] = s;
  __syncthreads();
  if (t < FT) sp[t] = part[t] + part[t + 128];
  __syncthreads();
  float a0 = B[t], a1 = B[t + 256];
  for (int k = 0; k < FT; ++k) {
    float xk = sp[k];
    a0 += xk * W[k * F1 + t];
    a1 += xk * W[k * F1 + t + 256];
  }
  O[g * F1 + t] = fmaxf(a0, 0.f);
  O[g * F1 + t + 256] = fmaxf(a1, 0.f);
}

// ---------------- MLP head ----------------

__global__ __launch_bounds__(256) void k_bnstats(const float* __restrict__ h, int cols,
                                                 float* __restrict__ bm, float* __restrict__ br) {
  __shared__ float ss[256], s2[256];
  int c = blockIdx.x, t = threadIdx.x;
  float a = 0.f, b = 0.f;
  for (int r = t; r < NG; r += 256) {
    float v = h[r * cols + c];
    a += v; b += v * v;
  }
  ss[t] = a; s2[t] = b; __syncthreads();
  for (int d = 128; d > 0; d >>= 1) {
    if (t < d) { ss[t] += ss[t + d]; s2[t] += s2[t + d]; }
    __syncthreads();
  }
  if (t == 0) {
    float m = ss[0] / NG;
    float var = s2[0] / NG - m * m;
    bm[c] = m;
    br[c] = rsqrtf(var + BN_EPS);
  }
}

__global__ __launch_bounds__(256) void k_fc2(const float* __restrict__ H1, const float* __restrict__ bm,
                                             const float* __restrict__ br, const float* __restrict__ gam,
                                             const float* __restrict__ bet, const float* __restrict__ W,
                                             const float* __restrict__ B, float* __restrict__ O) {
  __shared__ float sh[F1];
  int g = blockIdx.x, t = threadIdx.x;
  for (int k = t; k < F1; k += 256) {
    float v = H1[g * F1 + k];
    sh[k] = (v - bm[k]) * br[k] * gam[k] + bet[k];
  }
  __syncthreads();
  float a = B[t];
  for (int k = 0; k < F1; ++k) a += sh[k] * W[k * F2 + t];
  O[g * F2 + t] = fmaxf(a, 0.f);
}

__global__ __launch_bounds__(256) void k_fc3(const float* __restrict__ H2, const float* __restrict__ bm,
                                             const float* __restrict__ br, const float* __restrict__ gam,
                                             const float* __restrict__ bet, const float* __restrict__ W,
                                             const float* __restrict__ B, float* __restrict__ O) {
  __shared__ float sh[F2];
  int g = blockIdx.x, t = threadIdx.x;
  if (t < F2) {
    float v = H2[g * F2 + t];
    sh[t] = (v - bm[t]) * br[t] * gam[t] + bet[t];
  }
  __syncthreads();
  if (t < NC) {
    float a = B[t];
    for (int k = 0; k < F2; ++k) a += sh[k] * W[k * NC + t];
    O[g * NC + t] = 1.f / (1.f + expf(-a));
  }
}

// ---------------- launch ----------------

extern "C" void kernel_launch(void* const* d_in, const int* in_sizes, int n_in,
                              void* d_out, int out_size, void* d_ws, size_t ws_size,
                              hipStream_t stream) {
  const float* x     = (const float*)d_in[0];
  const int*   ei    = (const int*)d_in[1];
  const int*   batch = (const int*)d_in[2];
  const float* Wc[4] = {(const float*)d_in[3], (const float*)d_in[5], (const float*)d_in[7], (const float*)d_in[9]};
  const float* Bc[4] = {(const float*)d_in[4], (const float*)d_in[6], (const float*)d_in[8], (const float*)d_in[10]};
  const float* lw1 = (const float*)d_in[11]; const float* lb1 = (const float*)d_in[12];
  const float* lw2 = (const float*)d_in[13]; const float* lb2 = (const float*)d_in[14];
  const float* lw3 = (const float*)d_in[15]; const float* lb3 = (const float*)d_in[16];
  const float* g1  = (const float*)d_in[17]; const float* be1 = (const float*)d_in[18];
  const float* g2  = (const float*)d_in[19]; const float* be2 = (const float*)d_in[20];

  char* p = (char*)d_ws;
  auto take = [&](size_t bytes) {
    char* r = p;
    p += (bytes + 255) & ~(size_t)255;
    return r;
  };
  int*   cnt8   = (int*)take((size_t)8 * NN * 4);
  int*   cnt    = (int*)take((size_t)NN * 4);
  float* dinv   = (float*)take((size_t)NN * 4);
  int*   off    = (int*)take((size_t)(NN + 1) * 4);
  int*   bsum   = (int*)take(256 * 4);
  int*   bscan  = (int*)take(256 * 4);
  unsigned short* rank16 = (unsigned short*)take((size_t)NE * 2);
  unsigned int*   ep   = (unsigned int*)take((size_t)NE * 4);
  unsigned short* Wt   = (unsigned short*)take((size_t)4 * FT * FT * 2);
  unsigned short* bufT = (unsigned short*)take((size_t)NN * FT * 2);  // chunk-major fp16
  unsigned short* bufA = (unsigned short*)take((size_t)NN * FT * 2);
  unsigned short* bufB = (unsigned short*)take((size_t)NN * FT * 2);
  float* h1     = (float*)take((size_t)NG * F1 * 4);
  float* h2     = (float*)take((size_t)NG * F2 * 4);
  float* bnm1   = (float*)take(F1 * 4);
  float* bnr1   = (float*)take(F1 * 4);
  float* bnm2   = (float*)take(F2 * 4);
  float* bnr2   = (float*)take(F2 * 4);

  hipMemsetAsync(cnt8, 0, (size_t)8 * NN * 4, stream);

  k_hist<<<NSTRIP, 256, 0, stream>>>(ei, cnt8, rank16);
  k_sumdinv<<<NBLK, 256, 0, stream>>>(cnt8, cnt, dinv, bsum);
  k_scan2<<<1, 256, 0, stream>>>(bsum, bscan, NBLK);
  k_scan3<<<NBLK, 256, 0, stream>>>(cnt, bscan, off);
  k_fill<<<NSTRIP * 8, 256, 0, stream>>>(ei, off, cnt8, rank16, dinv, ep);
  k_wprep4<<<256, 256, 0, stream>>>(Wc[0], Wc[1], Wc[2], Wc[3], Wt);

  const int NBLK_G = (NN + 63) / 64;    // 782
  const int NGRP_A = (NN + 63) / 64;    // 782
  unsigned short* outs[4] = {bufA, bufB, bufA, bufB};
  for (int l = 0; l < 4; ++l) {
    if (l == 0)
      k_gemm_mfma<1><<<NBLK_G, 256, 0, stream>>>(x, (const unsigned short*)nullptr, Wt, bufT);
    else
      k_gemm_mfma<0><<<NBLK_G, 256, 0, stream>>>((const float*)nullptr, outs[l - 1], Wt + (size_t)l * FT * FT, bufT);
    k_aggc<<<NGRP_A * 4, 256, 0, stream>>>(bufT, dinv, off, ep, Bc[l], outs[l]);
  }

  k_poolfc1<<<NG, 256, 0, stream>>>(bufB, batch, lw1, lb1, h1);
  k_bnstats<<<F1, 256, 0, stream>>>(h1, F1, bnm1, bnr1);
  k_fc2<<<NG, 256, 0, stream>>>(h1, bnm1, bnr1, g1, be1, lw2, lb2, h2);
  k_bnstats<<<F2, 256, 0, stream>>>(h2, F2, bnm2, bnr2);
  k_fc3<<<NG, 256, 0, stream>>>(h2, bnm2, bnr2, g2, be2, lw3, lb3, (float*)d_out);
}